// Round 3
// baseline (232.752 us; speedup 1.0000x reference)
//
#include <hip/hip_runtime.h>
#include <hip/hip_bf16.h>
#include <math.h>

typedef __hip_bfloat16 bf16;
typedef __bf16  bf16x8 __attribute__((ext_vector_type(8)));
typedef float   f32x4  __attribute__((ext_vector_type(4)));

#define BB 2
#define NN 2048
#define DD 1024
#define HH 16
#define HD 64
#define LOG2E   1.44269504f
#define SCALE_Q 0.18033688f   /* 0.125 * log2(e), folded into q */

// async global->LDS, 16B/lane; LDS dest = wave-uniform base + lane*16
__device__ __forceinline__ void glds16(const bf16* g, bf16* l) {
    __builtin_amdgcn_global_load_lds((const __attribute__((address_space(1))) void*)g,
                                     (__attribute__((address_space(3))) void*)l, 16, 0, 0);
}
__device__ __forceinline__ unsigned short bfu(float x) {
    bf16 b = __float2bfloat16(x);
    return __builtin_bit_cast(unsigned short, b);
}

// ---------------------------------------------------------------------------
// prep (single launch): [0,2048) cast x ; [2048,3072) bias_perm fp32 (NEW
// 64q-block / k-split consumption order) ; [3072,3840) transpose Wqkv ;
// [3840,4096) coordproj.
// ---------------------------------------------------------------------------
__global__ __launch_bounds__(256) void prep(const float* __restrict__ x,
                                            const float* __restrict__ bias,
                                            const float* __restrict__ W,
                                            const float* __restrict__ coords,
                                            const float* __restrict__ relw,
                                            bf16* __restrict__ xb,
                                            float* __restrict__ pbf,
                                            bf16* __restrict__ Wt,
                                            bf16* __restrict__ cpn) {
    __shared__ bf16 tsm[64][65];
    const int bid = blockIdx.x, tid = threadIdx.x;
    if (bid < 2048) {
        size_t i = ((size_t)bid * 256 + tid) * 8;
        float4 a = *(const float4*)(x + i);
        float4 b = *(const float4*)(x + i + 4);
        bf16 t[8];
        t[0] = __float2bfloat16(a.x); t[1] = __float2bfloat16(a.y);
        t[2] = __float2bfloat16(a.z); t[3] = __float2bfloat16(a.w);
        t[4] = __float2bfloat16(b.x); t[5] = __float2bfloat16(b.y);
        t[6] = __float2bfloat16(b.z); t[7] = __float2bfloat16(b.w);
        *(int4*)(xb + i) = *(int4*)t;
    } else if (bid < 3072) {
        // pbf flat index f = (((Qb*32 + t)*8 + wave)*64 + lane)*8 + j, j=g*4+r
        // q = Qb*64 + (wave>>1)*16 + (lane>>4)*4 + r
        // k = t*64 + (wave&1)*32 + g*16 + (lane&15)
        int f0 = ((bid - 2048) * 256 + tid) * 16;
        float v[16];
#pragma unroll
        for (int u = 0; u < 16; ++u) {
            int f    = f0 + u;
            int j    = f & 7;
            int lane = (f >> 3) & 63;
            int wave = (f >> 9) & 7;
            int t    = (f >> 12) & 31;
            int Qb   = f >> 17;
            int q = Qb * 64 + ((wave >> 1) << 4) + ((lane >> 4) << 2) + (j & 3);
            int k = t * 64 + ((wave & 1) << 5) + ((j >> 2) << 4) + (lane & 15);
            v[u] = LOG2E * bias[(size_t)q * NN + k];
        }
        int4* dst = (int4*)(pbf + (size_t)f0);
#pragma unroll
        for (int i = 0; i < 4; ++i) dst[i] = ((int4*)v)[i];
    } else if (bid < 3840) {
        int idx = bid - 3072;                    // 0..767
        int n0 = (idx % 48) * 64;
        int k0 = (idx / 48) * 64;
        int tx = tid & 63, tg = tid >> 6;
#pragma unroll
        for (int i = 0; i < 16; ++i) {
            int r = tg + i * 4;
            tsm[r][tx] = __float2bfloat16(W[(size_t)(k0 + r) * 3072 + n0 + tx]);
        }
        __syncthreads();
#pragma unroll
        for (int i = 0; i < 16; ++i) {
            int r = tg + i * 4;
            Wt[(size_t)(n0 + r) * 1024 + k0 + tx] = tsm[tx][r];
        }
    } else {
        int idx = (bid - 3840) * 256 + tid;      // 0..65535
        int n  = idx & (NN - 1);
        int bh = idx >> 11;
        int h  = bh & (HH - 1);
        int b  = bh >> 4;
        float acc = 0.f;
#pragma unroll
        for (int c = 0; c < 3; ++c)
            acc += coords[(size_t)(b * NN + n) * 3 + c] * relw[h * 3 + c];
        cpn[idx] = __float2bfloat16(-LOG2E * acc);
    }
}

// ---------------------------------------------------------------------------
// qkv GEMM (R1 version, reverted): 128x128 tile, BK=32, glds w=16, swizzle
// c^=((row>>1)&3). V written DIRECTLY TRANSPOSED (bh,d,n); q pre-scaled.
// ---------------------------------------------------------------------------
__global__ __launch_bounds__(256) void qkv_gemm(const bf16* __restrict__ X,
                                                const bf16* __restrict__ W,
                                                const float* __restrict__ bq,
                                                bf16* __restrict__ qo,
                                                bf16* __restrict__ ko,
                                                bf16* __restrict__ vt) {
    __shared__ __align__(16) bf16 As[128 * 32];
    __shared__ __align__(16) bf16 Bs[128 * 32];
    const int tid  = threadIdx.x;
    const int n0   = blockIdx.x * 128;
    const int m0   = blockIdx.y * 128;
    const int wave = tid >> 6, lane = tid & 63, l15 = lane & 15, quad = lane >> 4;
    const int wm   = wave >> 1, wn = wave & 1;

    f32x4 acc[4][4];
    const f32x4 z4 = {0.f, 0.f, 0.f, 0.f};
#pragma unroll
    for (int i = 0; i < 4; ++i)
#pragma unroll
        for (int j = 0; j < 4; ++j) acc[i][j] = z4;

    for (int kt = 0; kt < 1024; kt += 32) {
        __syncthreads();
#pragma unroll
        for (int j = 0; j < 2; ++j) {
            int s   = (wave * 2 + j) * 64 + lane;       // 0..511
            int row = s >> 2;                           // 0..127
            int c   = (s & 3) ^ ((row >> 1) & 3);       // swizzled col-block
            glds16(X + (size_t)(m0 + row) * 1024 + kt + c * 8, As + (wave * 2 + j) * 512);
            glds16(W + (size_t)(n0 + row) * 1024 + kt + c * 8, Bs + (wave * 2 + j) * 512);
        }
        __syncthreads();

        bf16x8 a[4], b[4];
#pragma unroll
        for (int mt = 0; mt < 4; ++mt) {
            int ra = wm * 64 + mt * 16 + l15;
            a[mt] = *(const bf16x8*)&As[ra * 32 + ((quad ^ ((ra >> 1) & 3)) * 8)];
        }
#pragma unroll
        for (int nt = 0; nt < 4; ++nt) {
            int rb = wn * 64 + nt * 16 + l15;
            b[nt] = *(const bf16x8*)&Bs[rb * 32 + ((quad ^ ((rb >> 1) & 3)) * 8)];
        }
#pragma unroll
        for (int mt = 0; mt < 4; ++mt)
#pragma unroll
            for (int nt = 0; nt < 4; ++nt)
                acc[mt][nt] = __builtin_amdgcn_mfma_f32_16x16x32_bf16(a[mt], b[nt], acc[mt][nt], 0, 0, 0);
    }

#pragma unroll
    for (int nt = 0; nt < 4; ++nt) {
        int c    = n0 + wn * 64 + nt * 16 + l15;   // 0..3071, tsel uniform per nt
        int tsel = c >> 10;
        int rem  = c & 1023;
        int h    = rem >> 6, d = rem & 63;
        float bias = bq[c];
        float qs   = (tsel == 0) ? SCALE_Q : 1.0f;
#pragma unroll
        for (int mt = 0; mt < 4; ++mt)
#pragma unroll
            for (int r = 0; r < 4; ++r) {
                int m = m0 + wm * 64 + mt * 16 + quad * 4 + r;   // 0..4095
                int b = m >> 11, n = m & (NN - 1);
                bf16 val = __float2bfloat16((acc[mt][nt][r] + bias) * qs);
                if (tsel == 2)
                    vt[((size_t)(b * HH + h) * HD + d) * NN + n] = val;
                else
                    ((tsel == 1) ? ko : qo)[((size_t)(b * HH + h) * NN + n) * HD + d] = val;
            }
    }
}

// ---------------------------------------------------------------------------
// flash attention v3: 64 q/block, 8 waves = 4 q-groups x 2 k-halves.
// Grid 1024 (32 Qb x 32 bh); LDS 47104 B -> 3 blocks/CU (24 waves/CU).
// Per wave per tile: 2 QK MFMA-pairs (32 keys), 8 exp2, 4 pack words,
// sel-perm transpose, 4 PV MFMA. ws-pair O/l combine via LDS at end.
// ---------------------------------------------------------------------------
__global__ __launch_bounds__(512, 6) void attn(const bf16* __restrict__ Q,
                                               const bf16* __restrict__ K,
                                               const bf16* __restrict__ Vt_g,
                                               const bf16* __restrict__ cpn_g,
                                               const float* __restrict__ pbf,
                                               float* __restrict__ out) {
    __shared__ __align__(16) bf16 Ks[2][64 * 64];
    __shared__ __align__(16) bf16 Vs[2][64 * 64];      // [d][key]
    __shared__ __align__(16) unsigned PsW[8][16 * 20]; // packed P, per-wave
    __shared__ __align__(16) bf16 cpl[NN];             // -log2e * cp[bh][*]
    const int tid  = threadIdx.x;
    const int Qb   = blockIdx.x;           // 0..31
    const int bh   = blockIdx.y;           // 0..31
    const int b    = bh >> 4, h = bh & 15;
    const int q0   = Qb * 64;
    const int wave = tid >> 6, lane = tid & 63, l15 = lane & 15, quad = lane >> 4;
    const int wq   = wave >> 1, ws = wave & 1;
    const size_t base = (size_t)bh * NN * HD;

    // stage cp row (4 KB) with waves 0..3 (wave-uniform branch)
    if (wave < 4)
        glds16(cpn_g + bh * NN + (wave * 64 + lane) * 8, cpl + wave * 512);

    // Q fragments: 16 q-rows per wq pair (both halves load the same rows)
    const int qrow = q0 + wq * 16 + l15;
    bf16x8 qf0 = *(const bf16x8*)&Q[base + (size_t)qrow * HD + quad * 8];
    bf16x8 qf1 = *(const bf16x8*)&Q[base + (size_t)qrow * HD + 32 + quad * 8];

    // hoisted staging geometry (one glds per buffer per wave, all 8 waves)
    const int ps   = wave * 64 + lane;     // 0..511
    const int prow = ps >> 3;              // 0..63
    const int pcol = (ps & 7) ^ (prow & 7);

    // prologue: stage tile 0 into buffer 0
    glds16(K    + base + (size_t)prow * HD + pcol * 8, Ks[0] + wave * 512);
    glds16(Vt_g + base + (size_t)prow * NN + pcol * 8, Vs[0] + wave * 512);

    // bias: permuted fp32, register double-buffer. tile stride = 4096 floats.
    const float* bptr = pbf + (((size_t)(Qb * 32) * 8 + wave) * 64 + lane) * 8;
    float4 bvA[2], bvB[2];
    bvA[0] = ((const float4*)bptr)[0];
    bvA[1] = ((const float4*)bptr)[1];

    const f32x4 z4 = {0.f, 0.f, 0.f, 0.f};
    f32x4 l4 = z4;
    f32x4 o[4];
#pragma unroll
    for (int t = 0; t < 4; ++t) o[t] = z4;

#define ATTN_TILE(T, CUR, BVC, BVN)                                               \
    {                                                                             \
        __syncthreads();   /* buf[CUR] ready (vmcnt drained); buf[CUR^1] free */  \
        if ((T) < 31) {    /* prefetch K/V tile T+1 and bias T+1 */               \
            int kk1 = ((T) + 1) * 64;                                             \
            glds16(K    + base + (size_t)(kk1 + prow) * HD + pcol * 8,            \
                   Ks[(CUR) ^ 1] + wave * 512);                                   \
            glds16(Vt_g + base + (size_t)prow * NN + kk1 + pcol * 8,              \
                   Vs[(CUR) ^ 1] + wave * 512);                                   \
            const float* bp = bptr + (size_t)((T) + 1) * 4096;                    \
            BVN[0] = ((const float4*)bp)[0];                                      \
            BVN[1] = ((const float4*)bp)[1];                                      \
        }                                                                         \
        /* --- QK^T over this wave's 32-key half, C = bias' + mg */               \
        f32x4 p4[2];                                                              \
        _Pragma("unroll")                                                         \
        for (int g = 0; g < 2; ++g) {                                             \
            float mgv = __bfloat162float(cpl[(T) * 64 + ws * 32 + g * 16 + l15]); \
            f32x4 mg4 = {mgv, mgv, mgv, mgv};                                     \
            f32x4 c0  = __builtin_bit_cast(f32x4, BVC[g]) + mg4;                  \
            int krow = ws * 32 + g * 16 + l15, sw = krow & 7;                     \
            bf16x8 k0 = *(const bf16x8*)&Ks[(CUR)][krow * 64 + ((quad ^ sw) * 8)];         \
            bf16x8 k1 = *(const bf16x8*)&Ks[(CUR)][krow * 64 + (((4 + quad) ^ sw) * 8)];   \
            f32x4 s4 = __builtin_amdgcn_mfma_f32_16x16x32_bf16(qf0, k0, c0, 0, 0, 0);      \
            s4 = __builtin_amdgcn_mfma_f32_16x16x32_bf16(qf1, k1, s4, 0, 0, 0);   \
            f32x4 e;                                                              \
            e[0] = __builtin_amdgcn_exp2f(s4[0]);                                 \
            e[1] = __builtin_amdgcn_exp2f(s4[1]);                                 \
            e[2] = __builtin_amdgcn_exp2f(s4[2]);                                 \
            e[3] = __builtin_amdgcn_exp2f(s4[3]);                                 \
            p4[g] = e;                                                            \
            l4 = l4 + e;                                                          \
        }                                                                         \
        /* --- packed P write (4 b32): word w of row q = (k=w lo, k=w+16 hi) */   \
        _Pragma("unroll")                                                         \
        for (int r = 0; r < 4; ++r) {                                             \
            unsigned pk = (unsigned)bfu(p4[0][r]) | ((unsigned)bfu(p4[1][r]) << 16); \
            PsW[wave][(quad * 4 + r) * 20 + l15] = pk;                            \
        }                                                                         \
        asm volatile("s_waitcnt lgkmcnt(0)" ::: "memory");                        \
        const int4* pr = (const int4*)&PsW[wave][l15 * 20 + (quad & 1) * 8];      \
        int4 da = pr[0], db = pr[1];                                              \
        union { unsigned u[4]; bf16x8 v; } uu;                                    \
        unsigned sel = (quad < 2) ? 0x05040100u : 0x07060302u;                    \
        uu.u[0] = __builtin_amdgcn_perm(da.y, da.x, sel);                         \
        uu.u[1] = __builtin_amdgcn_perm(da.w, da.z, sel);                         \
        uu.u[2] = __builtin_amdgcn_perm(db.y, db.x, sel);                         \
        uu.u[3] = __builtin_amdgcn_perm(db.w, db.z, sel);                         \
        /* --- PV: one k=32 MFMA per 16-d group */                                \
        __builtin_amdgcn_s_setprio(1);                                            \
        _Pragma("unroll")                                                         \
        for (int tt = 0; tt < 4; ++tt) {                                          \
            int drow = tt * 16 + l15, sw2 = drow & 7;                             \
            bf16x8 vf = *(const bf16x8*)&Vs[(CUR)][drow * 64 + (((ws * 4 + quad) ^ sw2) * 8)]; \
            o[tt] = __builtin_amdgcn_mfma_f32_16x16x32_bf16(uu.v, vf, o[tt], 0, 0, 0);     \
        }                                                                         \
        __builtin_amdgcn_s_setprio(0);                                            \
    }

    for (int t = 0; t < 32; t += 2) {
        ATTN_TILE(t,     0, bvA, bvB)
        ATTN_TILE(t + 1, 1, bvB, bvA)
    }
#undef ATTN_TILE

    // l reduction within 16-lane groups (sum over this half's 32 keys)
    float l_loc[4] = {l4[0], l4[1], l4[2], l4[3]};
#pragma unroll
    for (int r = 0; r < 4; ++r)
#pragma unroll
        for (int d = 1; d < 16; d <<= 1)
            l_loc[r] += __shfl_xor(l_loc[r], d, 64);

    // ws-pair combine via LDS (reuse Ks for wq<2, Vs for wq>=2; stride 68,
    // word 64 of each row holds the partial l)
    float* obase = (wq < 2) ? (float*)Ks : (float*)Vs;
    const int rowl0 = (wq & 1) * 16;
    __syncthreads();                       // everyone done reading K/V tiles
    if (ws == 1) {
#pragma unroll
        for (int r = 0; r < 4; ++r) {
            int row = rowl0 + quad * 4 + r;
#pragma unroll
            for (int tt = 0; tt < 4; ++tt)
                obase[row * 68 + tt * 16 + l15] = o[tt][r];
            if (l15 == 0) obase[row * 68 + 64] = l_loc[r];
        }
    }
    __syncthreads();
    if (ws == 0) {
#pragma unroll
        for (int r = 0; r < 4; ++r) {
            int row = rowl0 + quad * 4 + r;
            float lt  = l_loc[r] + obase[row * 68 + 64];
            float inv = 1.0f / lt;
            int qq = q0 + wq * 16 + quad * 4 + r;
#pragma unroll
            for (int tt = 0; tt < 4; ++tt) {
                float ov = o[tt][r] + obase[row * 68 + tt * 16 + l15];
                out[((size_t)(b * NN + qq)) * DD + h * HD + tt * 16 + l15] = ov * inv;
            }
        }
    }
}

// ---------------------------------------------------------------------------
extern "C" void kernel_launch(void* const* d_in, const int* in_sizes, int n_in,
                              void* d_out, int out_size, void* d_ws, size_t ws_size,
                              hipStream_t stream) {
    const float* x      = (const float*)d_in[0];
    const float* coords = (const float*)d_in[1];
    const float* abias  = (const float*)d_in[2];
    const float* Wqkv   = (const float*)d_in[3];
    const float* bqkv   = (const float*)d_in[4];
    const float* relw   = (const float*)d_in[5];
    float* out = (float*)d_out;

    char* ws = (char*)d_ws;
    bf16*  xb  = (bf16*)(ws);                      // 8 MB
    bf16*  qw  = (bf16*)(ws + 8388608);            // 8 MB
    bf16*  kw  = (bf16*)(ws + 16777216);           // 8 MB
    bf16*  vt  = (bf16*)(ws + 25165824);           // 8 MB (bh,d,n) via gemm epilogue
    bf16*  Wt  = (bf16*)(ws + 33554432);           // 6 MB
    float* pbf = (float*)(ws + 39845888);          // 16 MB permuted bias fp32
    bf16*  cpb = (bf16*)(ws + 56623104);           // 128 KB

    prep    <<<dim3(4096),   256, 0, stream>>>(x, abias, Wqkv, coords, relw,
                                               xb, pbf, Wt, cpb);
    qkv_gemm<<<dim3(24, 32), 256, 0, stream>>>(xb, Wt, bqkv, qw, kw, vt);
    attn    <<<dim3(32, 32), 512, 0, stream>>>(qw, kw, vt, cpb, pbf, out);
}

// Round 4
// 205.743 us; speedup vs baseline: 1.1313x; 1.1313x over previous
//
#include <hip/hip_runtime.h>
#include <hip/hip_bf16.h>
#include <math.h>

typedef __hip_bfloat16 bf16;
typedef __bf16  bf16x8 __attribute__((ext_vector_type(8)));
typedef float   f32x4  __attribute__((ext_vector_type(4)));

#define BB 2
#define NN 2048
#define DD 1024
#define HH 16
#define HD 64
#define LOG2E   1.44269504f
#define SCALE_Q 0.18033688f   /* 0.125 * log2(e), folded into q */

// async global->LDS, 16B/lane; LDS dest = wave-uniform base + lane*16
__device__ __forceinline__ void glds16(const bf16* g, bf16* l) {
    __builtin_amdgcn_global_load_lds((const __attribute__((address_space(1))) void*)g,
                                     (__attribute__((address_space(3))) void*)l, 16, 0, 0);
}
__device__ __forceinline__ unsigned short bfu(float x) {
    bf16 b = __float2bfloat16(x);
    return __builtin_bit_cast(unsigned short, b);
}

// ---------------------------------------------------------------------------
// prep (single launch): [0,2048) cast x ; [2048,3072) bias_perm fp32 (4-wave
// x 2-qh consumption order for attn v4) ; [3072,3840) transpose Wqkv ;
// [3840,4096) coordproj.
// ---------------------------------------------------------------------------
__global__ __launch_bounds__(256) void prep(const float* __restrict__ x,
                                            const float* __restrict__ bias,
                                            const float* __restrict__ W,
                                            const float* __restrict__ coords,
                                            const float* __restrict__ relw,
                                            bf16* __restrict__ xb,
                                            float* __restrict__ pbf,
                                            bf16* __restrict__ Wt,
                                            bf16* __restrict__ cpn) {
    __shared__ bf16 tsm[64][65];
    const int bid = blockIdx.x, tid = threadIdx.x;
    if (bid < 2048) {
        size_t i = ((size_t)bid * 256 + tid) * 8;
        float4 a = *(const float4*)(x + i);
        float4 b = *(const float4*)(x + i + 4);
        bf16 t[8];
        t[0] = __float2bfloat16(a.x); t[1] = __float2bfloat16(a.y);
        t[2] = __float2bfloat16(a.z); t[3] = __float2bfloat16(a.w);
        t[4] = __float2bfloat16(b.x); t[5] = __float2bfloat16(b.y);
        t[6] = __float2bfloat16(b.z); t[7] = __float2bfloat16(b.w);
        *(int4*)(xb + i) = *(int4*)t;
    } else if (bid < 3072) {
        // pbf flat f = ((((Qb*32 + t)*4 + w)*2 + qh)*64 + lane)*16 + (g*4+r)
        // q = Qb*128 + w*32 + qh*16 + (lane>>4)*4 + r
        // k = t*64 + g*16 + (lane&15)
        int f0 = ((bid - 2048) * 256 + tid) * 16;
        float v[16];
#pragma unroll
        for (int u = 0; u < 16; ++u) {
            int f    = f0 + u;
            int j    = f & 15;
            int lane = (f >> 4) & 63;
            int qh   = (f >> 10) & 1;
            int w    = (f >> 11) & 3;
            int t    = (f >> 13) & 31;
            int Qb   = f >> 18;
            int q = Qb * 128 + w * 32 + qh * 16 + ((lane >> 4) << 2) + (j & 3);
            int k = t * 64 + ((j >> 2) << 4) + (lane & 15);
            v[u] = LOG2E * bias[(size_t)q * NN + k];
        }
        int4* dst = (int4*)(pbf + (size_t)f0);
#pragma unroll
        for (int i = 0; i < 4; ++i) dst[i] = ((int4*)v)[i];
    } else if (bid < 3840) {
        int idx = bid - 3072;                    // 0..767
        int n0 = (idx % 48) * 64;
        int k0 = (idx / 48) * 64;
        int tx = tid & 63, tg = tid >> 6;
#pragma unroll
        for (int i = 0; i < 16; ++i) {
            int r = tg + i * 4;
            tsm[r][tx] = __float2bfloat16(W[(size_t)(k0 + r) * 3072 + n0 + tx]);
        }
        __syncthreads();
#pragma unroll
        for (int i = 0; i < 16; ++i) {
            int r = tg + i * 4;
            Wt[(size_t)(n0 + r) * 1024 + k0 + tx] = tsm[tx][r];
        }
    } else {
        int idx = (bid - 3840) * 256 + tid;      // 0..65535
        int n  = idx & (NN - 1);
        int bh = idx >> 11;
        int h  = bh & (HH - 1);
        int b  = bh >> 4;
        float acc = 0.f;
#pragma unroll
        for (int c = 0; c < 3; ++c)
            acc += coords[(size_t)(b * NN + n) * 3 + c] * relw[h * 3 + c];
        cpn[idx] = __float2bfloat16(-LOG2E * acc);
    }
}

// ---------------------------------------------------------------------------
// qkv GEMM (R1 version): 128x128 tile, BK=32, glds w=16, swizzle
// c^=((row>>1)&3). V written DIRECTLY TRANSPOSED (bh,d,n); q pre-scaled.
// ---------------------------------------------------------------------------
__global__ __launch_bounds__(256) void qkv_gemm(const bf16* __restrict__ X,
                                                const bf16* __restrict__ W,
                                                const float* __restrict__ bq,
                                                bf16* __restrict__ qo,
                                                bf16* __restrict__ ko,
                                                bf16* __restrict__ vt) {
    __shared__ __align__(16) bf16 As[128 * 32];
    __shared__ __align__(16) bf16 Bs[128 * 32];
    const int tid  = threadIdx.x;
    const int n0   = blockIdx.x * 128;
    const int m0   = blockIdx.y * 128;
    const int wave = tid >> 6, lane = tid & 63, l15 = lane & 15, quad = lane >> 4;
    const int wm   = wave >> 1, wn = wave & 1;

    f32x4 acc[4][4];
    const f32x4 z4 = {0.f, 0.f, 0.f, 0.f};
#pragma unroll
    for (int i = 0; i < 4; ++i)
#pragma unroll
        for (int j = 0; j < 4; ++j) acc[i][j] = z4;

    for (int kt = 0; kt < 1024; kt += 32) {
        __syncthreads();
#pragma unroll
        for (int j = 0; j < 2; ++j) {
            int s   = (wave * 2 + j) * 64 + lane;       // 0..511
            int row = s >> 2;                           // 0..127
            int c   = (s & 3) ^ ((row >> 1) & 3);       // swizzled col-block
            glds16(X + (size_t)(m0 + row) * 1024 + kt + c * 8, As + (wave * 2 + j) * 512);
            glds16(W + (size_t)(n0 + row) * 1024 + kt + c * 8, Bs + (wave * 2 + j) * 512);
        }
        __syncthreads();

        bf16x8 a[4], b[4];
#pragma unroll
        for (int mt = 0; mt < 4; ++mt) {
            int ra = wm * 64 + mt * 16 + l15;
            a[mt] = *(const bf16x8*)&As[ra * 32 + ((quad ^ ((ra >> 1) & 3)) * 8)];
        }
#pragma unroll
        for (int nt = 0; nt < 4; ++nt) {
            int rb = wn * 64 + nt * 16 + l15;
            b[nt] = *(const bf16x8*)&Bs[rb * 32 + ((quad ^ ((rb >> 1) & 3)) * 8)];
        }
#pragma unroll
        for (int mt = 0; mt < 4; ++mt)
#pragma unroll
            for (int nt = 0; nt < 4; ++nt)
                acc[mt][nt] = __builtin_amdgcn_mfma_f32_16x16x32_bf16(a[mt], b[nt], acc[mt][nt], 0, 0, 0);
    }

#pragma unroll
    for (int nt = 0; nt < 4; ++nt) {
        int c    = n0 + wn * 64 + nt * 16 + l15;   // 0..3071, tsel uniform per nt
        int tsel = c >> 10;
        int rem  = c & 1023;
        int h    = rem >> 6, d = rem & 63;
        float bias = bq[c];
        float qs   = (tsel == 0) ? SCALE_Q : 1.0f;
#pragma unroll
        for (int mt = 0; mt < 4; ++mt)
#pragma unroll
            for (int r = 0; r < 4; ++r) {
                int m = m0 + wm * 64 + mt * 16 + quad * 4 + r;   // 0..4095
                int b = m >> 11, n = m & (NN - 1);
                bf16 val = __float2bfloat16((acc[mt][nt][r] + bias) * qs);
                if (tsel == 2)
                    vt[((size_t)(b * HH + h) * HD + d) * NN + n] = val;
                else
                    ((tsel == 1) ? ko : qo)[((size_t)(b * HH + h) * NN + n) * HD + d] = val;
            }
    }
}

// ---------------------------------------------------------------------------
// flash attention v4: 128 q/block, 4 waves x 32 q (2 qh halves of 16).
// Grid (16,32)=512 blocks, 2 blocks/CU. Each K/V LDS fragment read feeds
// TWO MFMAs (qh reuse) -> per-CU LDS-read traffic ~65% of v2. PsW transpose
// done per-qh through the same wave-private buffer (in-order DS). V frags
// held in regs across both qh halves. LDS 46080 B.
// ---------------------------------------------------------------------------
__global__ __launch_bounds__(256, 2) void attn(const bf16* __restrict__ Q,
                                               const bf16* __restrict__ K,
                                               const bf16* __restrict__ Vt_g,
                                               const bf16* __restrict__ cpn_g,
                                               const float* __restrict__ pbf,
                                               float* __restrict__ out) {
    __shared__ __align__(16) bf16 Ks[2][64 * 64];
    __shared__ __align__(16) bf16 Vs[2][64 * 64];      // [d][key]
    __shared__ __align__(16) unsigned PsW[4][16 * 36]; // packed P, per-wave
    __shared__ __align__(16) bf16 cpl[NN];             // -log2e * cp[bh][*]
    const int tid  = threadIdx.x;
    const int Qb   = blockIdx.x;           // 0..15
    const int bh   = blockIdx.y;           // 0..31
    const int b    = bh >> 4, h = bh & 15;
    const int q0   = Qb * 128;
    const int w    = tid >> 6, lane = tid & 63, l15 = lane & 15, quad = lane >> 4;
    const size_t base = (size_t)bh * NN * HD;

    // stage cp row (4 KB): all 4 waves, 512 bf16 each
    glds16(cpn_g + bh * NN + (w * 64 + lane) * 8, cpl + w * 512);

    // Q fragments: 32 q-rows per wave (two 16-row halves), resident all kernel
    const int qr0 = q0 + w * 32 + l15;
    bf16x8 qf00 = *(const bf16x8*)&Q[base + (size_t)qr0 * HD + quad * 8];
    bf16x8 qf01 = *(const bf16x8*)&Q[base + (size_t)qr0 * HD + 32 + quad * 8];
    bf16x8 qf10 = *(const bf16x8*)&Q[base + (size_t)(qr0 + 16) * HD + quad * 8];
    bf16x8 qf11 = *(const bf16x8*)&Q[base + (size_t)(qr0 + 16) * HD + 32 + quad * 8];

    // prologue: stage tile 0 into buffer 0 (2 sweeps per matrix per wave)
#pragma unroll
    for (int j = 0; j < 2; ++j) {
        int s   = j * 256 + w * 64 + lane;   // 0..511
        int row = s >> 3;                    // 0..63
        int c   = (s & 7) ^ (row & 7);
        glds16(K    + base + (size_t)row * HD + c * 8, Ks[0] + j * 2048 + w * 512);
        glds16(Vt_g + base + (size_t)row * NN + c * 8, Vs[0] + j * 2048 + w * 512);
    }

    // bias: permuted fp32, register double-buffer. qh stride 1024 fl,
    // tile stride 8192 fl.
    const float* bptr = pbf + ((((size_t)Qb * 32 * 4 + w) * 2) * 64 + lane) * 16;
    float4 bvA0[4], bvA1[4], bvB0[4], bvB1[4];
#pragma unroll
    for (int i = 0; i < 4; ++i) {
        bvA0[i] = ((const float4*)bptr)[i];
        bvA1[i] = ((const float4*)(bptr + 1024))[i];
    }

    const f32x4 z4 = {0.f, 0.f, 0.f, 0.f};
    f32x4 l40 = z4, l41 = z4;
    f32x4 o0[4], o1[4];
#pragma unroll
    for (int t = 0; t < 4; ++t) { o0[t] = z4; o1[t] = z4; }

#define ATTN_TILE(T, CUR, BC0, BC1, BN0, BN1)                                     \
    {                                                                             \
        __syncthreads();   /* buf[CUR] ready (vmcnt drained); buf[CUR^1] free */  \
        if ((T) < 31) {    /* prefetch K/V tile T+1 and bias T+1 */               \
            int kk1 = ((T) + 1) * 64;                                             \
            _Pragma("unroll")                                                     \
            for (int j = 0; j < 2; ++j) {                                         \
                int s   = j * 256 + w * 64 + lane;                                \
                int row = s >> 3;                                                 \
                int c   = (s & 7) ^ (row & 7);                                    \
                glds16(K    + base + (size_t)(kk1 + row) * HD + c * 8,            \
                       Ks[(CUR) ^ 1] + j * 2048 + w * 512);                       \
                glds16(Vt_g + base + (size_t)row * NN + kk1 + c * 8,              \
                       Vs[(CUR) ^ 1] + j * 2048 + w * 512);                       \
            }                                                                     \
            const float* bp = bptr + (size_t)((T) + 1) * 8192;                    \
            BN0[0] = ((const float4*)bp)[0];                                      \
            BN0[1] = ((const float4*)bp)[1];                                      \
            BN0[2] = ((const float4*)bp)[2];                                      \
            BN0[3] = ((const float4*)bp)[3];                                      \
            BN1[0] = ((const float4*)(bp + 1024))[0];                             \
            BN1[1] = ((const float4*)(bp + 1024))[1];                             \
            BN1[2] = ((const float4*)(bp + 1024))[2];                             \
            BN1[3] = ((const float4*)(bp + 1024))[3];                             \
        }                                                                         \
        /* --- QK^T both q-halves share each K fragment; C = bias' + mg */        \
        f32x4 p0[4], p1[4];                                                       \
        _Pragma("unroll")                                                         \
        for (int g = 0; g < 4; ++g) {                                             \
            float mgv = __bfloat162float(cpl[(T) * 64 + g * 16 + l15]);           \
            f32x4 mg4 = {mgv, mgv, mgv, mgv};                                     \
            f32x4 c00 = __builtin_bit_cast(f32x4, BC0[g]) + mg4;                  \
            f32x4 c01 = __builtin_bit_cast(f32x4, BC1[g]) + mg4;                  \
            int krow = g * 16 + l15, sw = krow & 7;                               \
            bf16x8 k0 = *(const bf16x8*)&Ks[(CUR)][krow * 64 + ((quad ^ sw) * 8)];         \
            bf16x8 k1 = *(const bf16x8*)&Ks[(CUR)][krow * 64 + (((4 + quad) ^ sw) * 8)];   \
            f32x4 s0 = __builtin_amdgcn_mfma_f32_16x16x32_bf16(qf00, k0, c00, 0, 0, 0);    \
            s0 = __builtin_amdgcn_mfma_f32_16x16x32_bf16(qf01, k1, s0, 0, 0, 0);  \
            f32x4 s1 = __builtin_amdgcn_mfma_f32_16x16x32_bf16(qf10, k0, c01, 0, 0, 0);    \
            s1 = __builtin_amdgcn_mfma_f32_16x16x32_bf16(qf11, k1, s1, 0, 0, 0);  \
            f32x4 e0, e1;                                                         \
            e0[0] = __builtin_amdgcn_exp2f(s0[0]);                                \
            e0[1] = __builtin_amdgcn_exp2f(s0[1]);                                \
            e0[2] = __builtin_amdgcn_exp2f(s0[2]);                                \
            e0[3] = __builtin_amdgcn_exp2f(s0[3]);                                \
            e1[0] = __builtin_amdgcn_exp2f(s1[0]);                                \
            e1[1] = __builtin_amdgcn_exp2f(s1[1]);                                \
            e1[2] = __builtin_amdgcn_exp2f(s1[2]);                                \
            e1[3] = __builtin_amdgcn_exp2f(s1[3]);                                \
            p0[g] = e0; l40 = l40 + e0;                                           \
            p1[g] = e1; l41 = l41 + e1;                                           \
        }                                                                         \
        /* --- qh0: pack P, write, drain, read back as A-frags */                 \
        _Pragma("unroll")                                                         \
        for (int g2 = 0; g2 < 2; ++g2)                                            \
            _Pragma("unroll")                                                     \
            for (int r = 0; r < 4; ++r) {                                         \
                unsigned pk = (unsigned)bfu(p0[g2][r]) |                          \
                              ((unsigned)bfu(p0[g2 + 2][r]) << 16);               \
                PsW[w][(quad * 4 + r) * 36 + g2 * 16 + l15] = pk;                 \
            }                                                                     \
        asm volatile("s_waitcnt lgkmcnt(0)" ::: "memory");                        \
        union { unsigned u[4]; bf16x8 v; } uA0, uA1;                              \
        {                                                                         \
            const int4* pr = (const int4*)&PsW[w][l15 * 36 + quad * 8];           \
            int4 da = pr[0], db = pr[1];                                          \
            uA0.u[0] = __builtin_amdgcn_perm(da.y, da.x, 0x05040100u);            \
            uA0.u[1] = __builtin_amdgcn_perm(da.w, da.z, 0x05040100u);            \
            uA0.u[2] = __builtin_amdgcn_perm(db.y, db.x, 0x05040100u);            \
            uA0.u[3] = __builtin_amdgcn_perm(db.w, db.z, 0x05040100u);            \
            uA1.u[0] = __builtin_amdgcn_perm(da.y, da.x, 0x07060302u);            \
            uA1.u[1] = __builtin_amdgcn_perm(da.w, da.z, 0x07060302u);            \
            uA1.u[2] = __builtin_amdgcn_perm(db.y, db.x, 0x07060302u);            \
            uA1.u[3] = __builtin_amdgcn_perm(db.w, db.z, 0x07060302u);            \
        }                                                                         \
        /* --- V fragments into regs (shared by both q-halves) */                 \
        bf16x8 vf0[4], vf1[4];                                                    \
        _Pragma("unroll")                                                         \
        for (int tt = 0; tt < 4; ++tt) {                                          \
            int drow = tt * 16 + l15, sw2 = drow & 7;                             \
            vf0[tt] = *(const bf16x8*)&Vs[(CUR)][drow * 64 + ((quad ^ sw2) * 8)];          \
            vf1[tt] = *(const bf16x8*)&Vs[(CUR)][drow * 64 + (((4 + quad) ^ sw2) * 8)];    \
        }                                                                         \
        /* --- PV qh0 */                                                          \
        __builtin_amdgcn_s_setprio(1);                                            \
        _Pragma("unroll")                                                         \
        for (int tt = 0; tt < 4; ++tt) {                                          \
            o0[tt] = __builtin_amdgcn_mfma_f32_16x16x32_bf16(uA0.v, vf0[tt], o0[tt], 0, 0, 0); \
            o0[tt] = __builtin_amdgcn_mfma_f32_16x16x32_bf16(uA1.v, vf1[tt], o0[tt], 0, 0, 0); \
        }                                                                         \
        __builtin_amdgcn_s_setprio(0);                                            \
        /* --- qh1: pack P (same PsW region; per-wave in-order DS) */             \
        _Pragma("unroll")                                                         \
        for (int g2 = 0; g2 < 2; ++g2)                                            \
            _Pragma("unroll")                                                     \
            for (int r = 0; r < 4; ++r) {                                         \
                unsigned pk = (unsigned)bfu(p1[g2][r]) |                          \
                              ((unsigned)bfu(p1[g2 + 2][r]) << 16);               \
                PsW[w][(quad * 4 + r) * 36 + g2 * 16 + l15] = pk;                 \
            }                                                                     \
        asm volatile("s_waitcnt lgkmcnt(0)" ::: "memory");                        \
        union { unsigned u[4]; bf16x8 v; } uB0, uB1;                              \
        {                                                                         \
            const int4* pr = (const int4*)&PsW[w][l15 * 36 + quad * 8];           \
            int4 da = pr[0], db = pr[1];                                          \
            uB0.u[0] = __builtin_amdgcn_perm(da.y, da.x, 0x05040100u);            \
            uB0.u[1] = __builtin_amdgcn_perm(da.w, da.z, 0x05040100u);            \
            uB0.u[2] = __builtin_amdgcn_perm(db.y, db.x, 0x05040100u);            \
            uB0.u[3] = __builtin_amdgcn_perm(db.w, db.z, 0x05040100u);            \
            uB1.u[0] = __builtin_amdgcn_perm(da.y, da.x, 0x07060302u);            \
            uB1.u[1] = __builtin_amdgcn_perm(da.w, da.z, 0x07060302u);            \
            uB1.u[2] = __builtin_amdgcn_perm(db.y, db.x, 0x07060302u);            \
            uB1.u[3] = __builtin_amdgcn_perm(db.w, db.z, 0x07060302u);            \
        }                                                                         \
        /* --- PV qh1 (reuses vf regs) */                                         \
        __builtin_amdgcn_s_setprio(1);                                            \
        _Pragma("unroll")                                                         \
        for (int tt = 0; tt < 4; ++tt) {                                          \
            o1[tt] = __builtin_amdgcn_mfma_f32_16x16x32_bf16(uB0.v, vf0[tt], o1[tt], 0, 0, 0); \
            o1[tt] = __builtin_amdgcn_mfma_f32_16x16x32_bf16(uB1.v, vf1[tt], o1[tt], 0, 0, 0); \
        }                                                                         \
        __builtin_amdgcn_s_setprio(0);                                            \
    }

    for (int t = 0; t < 32; t += 2) {
        ATTN_TILE(t,     0, bvA0, bvA1, bvB0, bvB1)
        ATTN_TILE(t + 1, 1, bvB0, bvB1, bvA0, bvA1)
    }
#undef ATTN_TILE

    // final l reductions (16-lane groups) + fp32 stores, per q-half
    float la[4] = {l40[0], l40[1], l40[2], l40[3]};
    float lb[4] = {l41[0], l41[1], l41[2], l41[3]};
#pragma unroll
    for (int r = 0; r < 4; ++r) {
#pragma unroll
        for (int d = 1; d < 16; d <<= 1) {
            la[r] += __shfl_xor(la[r], d, 64);
            lb[r] += __shfl_xor(lb[r], d, 64);
        }
        float inva = 1.0f / la[r];
        float invb = 1.0f / lb[r];
        int qa = q0 + w * 32 + quad * 4 + r;
        int qb2 = qa + 16;
#pragma unroll
        for (int tt = 0; tt < 4; ++tt) {
            out[((size_t)(b * NN + qa))  * DD + h * HD + tt * 16 + l15] = o0[tt][r] * inva;
            out[((size_t)(b * NN + qb2)) * DD + h * HD + tt * 16 + l15] = o1[tt][r] * invb;
        }
    }
}

// ---------------------------------------------------------------------------
extern "C" void kernel_launch(void* const* d_in, const int* in_sizes, int n_in,
                              void* d_out, int out_size, void* d_ws, size_t ws_size,
                              hipStream_t stream) {
    const float* x      = (const float*)d_in[0];
    const float* coords = (const float*)d_in[1];
    const float* abias  = (const float*)d_in[2];
    const float* Wqkv   = (const float*)d_in[3];
    const float* bqkv   = (const float*)d_in[4];
    const float* relw   = (const float*)d_in[5];
    float* out = (float*)d_out;

    char* ws = (char*)d_ws;
    bf16*  xb  = (bf16*)(ws);                      // 8 MB
    bf16*  qw  = (bf16*)(ws + 8388608);            // 8 MB
    bf16*  kw  = (bf16*)(ws + 16777216);           // 8 MB
    bf16*  vt  = (bf16*)(ws + 25165824);           // 8 MB (bh,d,n) via gemm epilogue
    bf16*  Wt  = (bf16*)(ws + 33554432);           // 6 MB
    float* pbf = (float*)(ws + 39845888);          // 16 MB permuted bias fp32
    bf16*  cpb = (bf16*)(ws + 56623104);           // 128 KB

    prep    <<<dim3(4096),   256, 0, stream>>>(x, abias, Wqkv, coords, relw,
                                               xb, pbf, Wt, cpb);
    qkv_gemm<<<dim3(24, 32), 256, 0, stream>>>(xb, Wt, bqkv, qw, kw, vt);
    attn    <<<dim3(16, 32), 256, 0, stream>>>(qw, kw, vt, cpb, pbf, out);
}

// Round 6
// 197.153 us; speedup vs baseline: 1.1806x; 1.0436x over previous
//
#include <hip/hip_runtime.h>
#include <hip/hip_bf16.h>
#include <math.h>

typedef __hip_bfloat16 bf16;
typedef __bf16  bf16x8 __attribute__((ext_vector_type(8)));
typedef float   f32x4  __attribute__((ext_vector_type(4)));

#define BB 2
#define NN 2048
#define DD 1024
#define HH 16
#define HD 64
#define LOG2E   1.44269504f
#define SCALE_Q 0.18033688f   /* 0.125 * log2(e), folded into q */

// async global->LDS, 16B/lane; LDS dest = wave-uniform base + lane*16
__device__ __forceinline__ void glds16(const bf16* g, bf16* l) {
    __builtin_amdgcn_global_load_lds((const __attribute__((address_space(1))) void*)g,
                                     (__attribute__((address_space(3))) void*)l, 16, 0, 0);
}
__device__ __forceinline__ unsigned short bfu(float x) {
    bf16 b = __float2bfloat16(x);
    return __builtin_bit_cast(unsigned short, b);
}

// ---------------------------------------------------------------------------
// prep (single launch): [0,2048) cast x ; [2048,3072) bias_perm PACKED BF16
// pairs (8-wave consumption order; halves the dominant attn traffic stream) ;
// [3072,3840) transpose Wqkv ; [3840,4096) coordproj.
// ---------------------------------------------------------------------------
__global__ __launch_bounds__(256) void prep(const float* __restrict__ x,
                                            const float* __restrict__ bias,
                                            const float* __restrict__ W,
                                            const float* __restrict__ coords,
                                            const float* __restrict__ relw,
                                            bf16* __restrict__ xb,
                                            unsigned* __restrict__ pbh,
                                            bf16* __restrict__ Wt,
                                            bf16* __restrict__ cpn) {
    __shared__ bf16 tsm[64][65];
    const int bid = blockIdx.x, tid = threadIdx.x;
    if (bid < 2048) {
        size_t i = ((size_t)bid * 256 + tid) * 8;
        float4 a = *(const float4*)(x + i);
        float4 b = *(const float4*)(x + i + 4);
        bf16 t[8];
        t[0] = __float2bfloat16(a.x); t[1] = __float2bfloat16(a.y);
        t[2] = __float2bfloat16(a.z); t[3] = __float2bfloat16(a.w);
        t[4] = __float2bfloat16(b.x); t[5] = __float2bfloat16(b.y);
        t[6] = __float2bfloat16(b.z); t[7] = __float2bfloat16(b.w);
        *(int4*)(xb + i) = *(int4*)t;
    } else if (bid < 3072) {
        // pbh[tt*8 + m] packs bf16(log2e*bias) rows (quad*4+(m&1)*2, +1) at
        // col kt*64+(m>>1)*16+l15 ; tt = ((Qb*32+kt)*8+wave)*64+lane
        int tt   = (bid - 2048) * 256 + tid;     // 0..262143
        int lane = tt & 63;
        int wave = (tt >> 6) & 7;
        int kt   = (tt >> 9) & 31;
        int Qb   = tt >> 14;
        int quad = lane >> 4, l15 = lane & 15;
        unsigned pk[8];
#pragma unroll
        for (int m = 0; m < 8; ++m) {
            int g = m >> 1, rp = m & 1;
            int q = Qb * 128 + wave * 16 + quad * 4 + rp * 2;
            int k = kt * 64 + g * 16 + l15;
            float v0 = LOG2E * bias[(size_t)q * NN + k];
            float v1 = LOG2E * bias[(size_t)(q + 1) * NN + k];
            pk[m] = (unsigned)bfu(v0) | ((unsigned)bfu(v1) << 16);
        }
        int4* dst = (int4*)(pbh + (size_t)tt * 8);
        dst[0] = ((int4*)pk)[0];
        dst[1] = ((int4*)pk)[1];
    } else if (bid < 3840) {
        int idx = bid - 3072;                    // 0..767
        int n0 = (idx % 48) * 64;
        int k0 = (idx / 48) * 64;
        int tx = tid & 63, tg = tid >> 6;
#pragma unroll
        for (int i = 0; i < 16; ++i) {
            int r = tg + i * 4;
            tsm[r][tx] = __float2bfloat16(W[(size_t)(k0 + r) * 3072 + n0 + tx]);
        }
        __syncthreads();
#pragma unroll
        for (int i = 0; i < 16; ++i) {
            int r = tg + i * 4;
            Wt[(size_t)(n0 + r) * 1024 + k0 + tx] = tsm[tx][r];
        }
    } else {
        int idx = (bid - 3840) * 256 + tid;      // 0..65535
        int n  = idx & (NN - 1);
        int bh = idx >> 11;
        int h  = bh & (HH - 1);
        int b  = bh >> 4;
        float acc = 0.f;
#pragma unroll
        for (int c = 0; c < 3; ++c)
            acc += coords[(size_t)(b * NN + n) * 3 + c] * relw[h * 3 + c];
        cpn[idx] = __float2bfloat16(-LOG2E * acc);
    }
}

// ---------------------------------------------------------------------------
// qkv GEMM (R1 version): 128x128 tile, BK=32, glds w=16, swizzle
// c^=((row>>1)&3). V written DIRECTLY TRANSPOSED (bh,d,n); q pre-scaled.
// ---------------------------------------------------------------------------
__global__ __launch_bounds__(256) void qkv_gemm(const bf16* __restrict__ X,
                                                const bf16* __restrict__ W,
                                                const float* __restrict__ bq,
                                                bf16* __restrict__ qo,
                                                bf16* __restrict__ ko,
                                                bf16* __restrict__ vt) {
    __shared__ __align__(16) bf16 As[128 * 32];
    __shared__ __align__(16) bf16 Bs[128 * 32];
    const int tid  = threadIdx.x;
    const int n0   = blockIdx.x * 128;
    const int m0   = blockIdx.y * 128;
    const int wave = tid >> 6, lane = tid & 63, l15 = lane & 15, quad = lane >> 4;
    const int wm   = wave >> 1, wn = wave & 1;

    f32x4 acc[4][4];
    const f32x4 z4 = {0.f, 0.f, 0.f, 0.f};
#pragma unroll
    for (int i = 0; i < 4; ++i)
#pragma unroll
        for (int j = 0; j < 4; ++j) acc[i][j] = z4;

    for (int kt = 0; kt < 1024; kt += 32) {
        __syncthreads();
#pragma unroll
        for (int j = 0; j < 2; ++j) {
            int s   = (wave * 2 + j) * 64 + lane;       // 0..511
            int row = s >> 2;                           // 0..127
            int c   = (s & 3) ^ ((row >> 1) & 3);       // swizzled col-block
            glds16(X + (size_t)(m0 + row) * 1024 + kt + c * 8, As + (wave * 2 + j) * 512);
            glds16(W + (size_t)(n0 + row) * 1024 + kt + c * 8, Bs + (wave * 2 + j) * 512);
        }
        __syncthreads();

        bf16x8 a[4], b[4];
#pragma unroll
        for (int mt = 0; mt < 4; ++mt) {
            int ra = wm * 64 + mt * 16 + l15;
            a[mt] = *(const bf16x8*)&As[ra * 32 + ((quad ^ ((ra >> 1) & 3)) * 8)];
        }
#pragma unroll
        for (int nt = 0; nt < 4; ++nt) {
            int rb = wn * 64 + nt * 16 + l15;
            b[nt] = *(const bf16x8*)&Bs[rb * 32 + ((quad ^ ((rb >> 1) & 3)) * 8)];
        }
#pragma unroll
        for (int mt = 0; mt < 4; ++mt)
#pragma unroll
            for (int nt = 0; nt < 4; ++nt)
                acc[mt][nt] = __builtin_amdgcn_mfma_f32_16x16x32_bf16(a[mt], b[nt], acc[mt][nt], 0, 0, 0);
    }

#pragma unroll
    for (int nt = 0; nt < 4; ++nt) {
        int c    = n0 + wn * 64 + nt * 16 + l15;   // 0..3071, tsel uniform per nt
        int tsel = c >> 10;
        int rem  = c & 1023;
        int h    = rem >> 6, d = rem & 63;
        float bias = bq[c];
        float qs   = (tsel == 0) ? SCALE_Q : 1.0f;
#pragma unroll
        for (int mt = 0; mt < 4; ++mt)
#pragma unroll
            for (int r = 0; r < 4; ++r) {
                int m = m0 + wm * 64 + mt * 16 + quad * 4 + r;   // 0..4095
                int b = m >> 11, n = m & (NN - 1);
                bf16 val = __float2bfloat16((acc[mt][nt][r] + bias) * qs);
                if (tsel == 2)
                    vt[((size_t)(b * HH + h) * HD + d) * NN + n] = val;
                else
                    ((tsel == 1) ? ko : qo)[((size_t)(b * HH + h) * NN + n) * HD + d] = val;
            }
    }
}

// ---------------------------------------------------------------------------
// flash attention v5: R1 structure (512 thr = 8 waves x 16 q, 128 q/block,
// grid 512) + PACKED BF16 bias (2 int4 loads/tile instead of 4; unpack via
// shift/mask into the MFMA C-operand). Bias stream 536->268 MB logical.
// LDS 55296 B.
// ---------------------------------------------------------------------------
__global__ __launch_bounds__(512, 4) void attn(const bf16* __restrict__ Q,
                                               const bf16* __restrict__ K,
                                               const bf16* __restrict__ Vt_g,
                                               const bf16* __restrict__ cpn_g,
                                               const unsigned* __restrict__ pbh,
                                               float* __restrict__ out) {
    __shared__ __align__(16) bf16 Ks[2][64 * 64];
    __shared__ __align__(16) bf16 Vs[2][64 * 64];      // [d][key]
    __shared__ __align__(16) unsigned PsW[8][16 * 36]; // packed P, per-wave
    __shared__ __align__(16) bf16 cpl[NN];             // -log2e * cp[bh][*]
    const int tid  = threadIdx.x;
    const int Qb   = blockIdx.x;           // 0..15
    const int bh   = blockIdx.y;           // 0..31
    const int b    = bh >> 4, h = bh & 15;
    const int q0   = Qb * 128;
    const int wave = tid >> 6, lane = tid & 63, l15 = lane & 15, quad = lane >> 4;
    const size_t base = (size_t)bh * NN * HD;

    // stage cp row (4 KB) with waves 0..3 (wave-uniform branch)
    if (wave < 4)
        glds16(cpn_g + bh * NN + (wave * 64 + lane) * 8, cpl + wave * 512);

    // Q fragments: 16 q-rows per wave, in registers for the whole kernel
    const int qrow = q0 + wave * 16 + l15;
    bf16x8 qf0 = *(const bf16x8*)&Q[base + (size_t)qrow * HD + quad * 8];
    bf16x8 qf1 = *(const bf16x8*)&Q[base + (size_t)qrow * HD + 32 + quad * 8];

    // hoisted staging geometry (one glds per buffer per wave)
    const int ps   = wave * 64 + lane;     // 0..511
    const int prow = ps >> 3;              // 0..63
    const int pcol = (ps & 7) ^ (prow & 7);

    // prologue: stage tile 0 into buffer 0
    glds16(K    + base + (size_t)prow * HD + pcol * 8, Ks[0] + wave * 512);
    glds16(Vt_g + base + (size_t)prow * NN + pcol * 8, Vs[0] + wave * 512);

    // bias: permuted packed bf16, register double-buffer. tile stride 4096 u32.
    const unsigned* bptr = pbh + ((((size_t)Qb * 32) * 8 + wave) * 64 + lane) * 8;
    unsigned bvA[8], bvB[8];
    *(int4*)&bvA[0] = ((const int4*)bptr)[0];
    *(int4*)&bvA[4] = ((const int4*)bptr)[1];

    const f32x4 z4 = {0.f, 0.f, 0.f, 0.f};
    f32x4 l4 = z4;
    f32x4 o[4];
#pragma unroll
    for (int t = 0; t < 4; ++t) o[t] = z4;

#define ATTN_TILE(T, CUR, BVC, BVN)                                               \
    {                                                                             \
        __syncthreads();   /* buf[CUR] ready (vmcnt drained); buf[CUR^1] free */  \
        if ((T) < 31) {    /* prefetch K/V tile T+1 and bias T+1 */               \
            int kk1 = ((T) + 1) * 64;                                             \
            glds16(K    + base + (size_t)(kk1 + prow) * HD + pcol * 8,            \
                   Ks[(CUR) ^ 1] + wave * 512);                                   \
            glds16(Vt_g + base + (size_t)prow * NN + kk1 + pcol * 8,              \
                   Vs[(CUR) ^ 1] + wave * 512);                                   \
            const unsigned* bp = bptr + (size_t)((T) + 1) * 4096;                 \
            *(int4*)&BVN[0] = ((const int4*)bp)[0];                               \
            *(int4*)&BVN[4] = ((const int4*)bp)[1];                               \
        }                                                                         \
        /* --- QK^T with C = bias' + mg (bias unpacked bf16->f32 into C) */       \
        f32x4 p4[4];                                                              \
        _Pragma("unroll")                                                         \
        for (int g = 0; g < 4; ++g) {                                             \
            float mgv = __bfloat162float(cpl[(T) * 64 + g * 16 + l15]);           \
            unsigned ba = BVC[g * 2], bb2 = BVC[g * 2 + 1];                       \
            f32x4 c0;                                                             \
            c0[0] = __builtin_bit_cast(float, ba << 16) + mgv;                    \
            c0[1] = __builtin_bit_cast(float, ba & 0xffff0000u) + mgv;            \
            c0[2] = __builtin_bit_cast(float, bb2 << 16) + mgv;                   \
            c0[3] = __builtin_bit_cast(float, bb2 & 0xffff0000u) + mgv;           \
            int krow = g * 16 + l15, sw = krow & 7;                               \
            bf16x8 k0 = *(const bf16x8*)&Ks[(CUR)][krow * 64 + ((quad ^ sw) * 8)];         \
            bf16x8 k1 = *(const bf16x8*)&Ks[(CUR)][krow * 64 + (((4 + quad) ^ sw) * 8)];   \
            f32x4 s4 = __builtin_amdgcn_mfma_f32_16x16x32_bf16(qf0, k0, c0, 0, 0, 0);      \
            s4 = __builtin_amdgcn_mfma_f32_16x16x32_bf16(qf1, k1, s4, 0, 0, 0);   \
            f32x4 e;                                                              \
            e[0] = __builtin_amdgcn_exp2f(s4[0]);                                 \
            e[1] = __builtin_amdgcn_exp2f(s4[1]);                                 \
            e[2] = __builtin_amdgcn_exp2f(s4[2]);                                 \
            e[3] = __builtin_amdgcn_exp2f(s4[3]);                                 \
            p4[g] = e;                                                            \
            l4 = l4 + e;                                                          \
        }                                                                         \
        /* --- packed P write (8 b32), one wait, read back as A-frags */          \
        _Pragma("unroll")                                                         \
        for (int g2 = 0; g2 < 2; ++g2)                                            \
            _Pragma("unroll")                                                     \
            for (int r = 0; r < 4; ++r) {                                         \
                unsigned pk = (unsigned)bfu(p4[g2][r]) |                          \
                              ((unsigned)bfu(p4[g2 + 2][r]) << 16);               \
                PsW[wave][(quad * 4 + r) * 36 + g2 * 16 + l15] = pk;              \
            }                                                                     \
        asm volatile("s_waitcnt lgkmcnt(0)" ::: "memory");                        \
        const int4* pr = (const int4*)&PsW[wave][l15 * 36 + quad * 8];            \
        int4 da = pr[0], db = pr[1];                                              \
        union { unsigned u[4]; bf16x8 v; } u0, u1;                                \
        u0.u[0] = __builtin_amdgcn_perm(da.y, da.x, 0x05040100u);                 \
        u0.u[1] = __builtin_amdgcn_perm(da.w, da.z, 0x05040100u);                 \
        u0.u[2] = __builtin_amdgcn_perm(db.y, db.x, 0x05040100u);                 \
        u0.u[3] = __builtin_amdgcn_perm(db.w, db.z, 0x05040100u);                 \
        u1.u[0] = __builtin_amdgcn_perm(da.y, da.x, 0x07060302u);                 \
        u1.u[1] = __builtin_amdgcn_perm(da.w, da.z, 0x07060302u);                 \
        u1.u[2] = __builtin_amdgcn_perm(db.y, db.x, 0x07060302u);                 \
        u1.u[3] = __builtin_amdgcn_perm(db.w, db.z, 0x07060302u);                 \
        /* --- PV (V frags loaded at use) */                                      \
        __builtin_amdgcn_s_setprio(1);                                            \
        _Pragma("unroll")                                                         \
        for (int tt = 0; tt < 4; ++tt) {                                          \
            int drow = tt * 16 + l15, sw2 = drow & 7;                             \
            bf16x8 v0 = *(const bf16x8*)&Vs[(CUR)][drow * 64 + ((quad ^ sw2) * 8)];        \
            bf16x8 v1 = *(const bf16x8*)&Vs[(CUR)][drow * 64 + (((4 + quad) ^ sw2) * 8)];  \
            o[tt] = __builtin_amdgcn_mfma_f32_16x16x32_bf16(u0.v, v0, o[tt], 0, 0, 0);     \
            o[tt] = __builtin_amdgcn_mfma_f32_16x16x32_bf16(u1.v, v1, o[tt], 0, 0, 0);     \
        }                                                                         \
        __builtin_amdgcn_s_setprio(0);                                            \
    }

    for (int t = 0; t < 32; t += 2) {
        ATTN_TILE(t,     0, bvA, bvB)
        ATTN_TILE(t + 1, 1, bvB, bvA)
    }
#undef ATTN_TILE

    // final l reduction (16 lanes per quad-row) + fp32 stores
    float l_loc[4] = {l4[0], l4[1], l4[2], l4[3]};
#pragma unroll
    for (int r = 0; r < 4; ++r) {
#pragma unroll
        for (int d = 1; d < 16; d <<= 1)
            l_loc[r] += __shfl_xor(l_loc[r], d, 64);
        float inv = 1.0f / l_loc[r];
        int qq = q0 + wave * 16 + quad * 4 + r;
#pragma unroll
        for (int tt = 0; tt < 4; ++tt)
            out[((size_t)(b * NN + qq)) * DD + h * HD + tt * 16 + l15] =
                o[tt][r] * inv;
    }
}

// ---------------------------------------------------------------------------
extern "C" void kernel_launch(void* const* d_in, const int* in_sizes, int n_in,
                              void* d_out, int out_size, void* d_ws, size_t ws_size,
                              hipStream_t stream) {
    const float* x      = (const float*)d_in[0];
    const float* coords = (const float*)d_in[1];
    const float* abias  = (const float*)d_in[2];
    const float* Wqkv   = (const float*)d_in[3];
    const float* bqkv   = (const float*)d_in[4];
    const float* relw   = (const float*)d_in[5];
    float* out = (float*)d_out;

    char* ws = (char*)d_ws;
    bf16*     xb  = (bf16*)(ws);                      // 8 MB
    bf16*     qw  = (bf16*)(ws + 8388608);            // 8 MB
    bf16*     kw  = (bf16*)(ws + 16777216);           // 8 MB
    bf16*     vt  = (bf16*)(ws + 25165824);           // 8 MB (bh,d,n) via gemm epilogue
    bf16*     Wt  = (bf16*)(ws + 33554432);           // 6 MB
    unsigned* pbh = (unsigned*)(ws + 39845888);       // 8.4 MB permuted bias packed bf16
    bf16*     cpb = (bf16*)(ws + 56623104);           // 128 KB

    prep    <<<dim3(4096),   256, 0, stream>>>(x, abias, Wqkv, coords, relw,
                                               xb, pbh, Wt, cpb);
    qkv_gemm<<<dim3(24, 32), 256, 0, stream>>>(xb, Wt, bqkv, qw, kw, vt);
    attn    <<<dim3(16, 32), 512, 0, stream>>>(qw, kw, vt, cpb, pbh, out);
}

// Round 7
// 191.321 us; speedup vs baseline: 1.2165x; 1.0305x over previous
//
#include <hip/hip_runtime.h>
#include <hip/hip_bf16.h>
#include <math.h>

typedef __hip_bfloat16 bf16;
typedef __bf16  bf16x8 __attribute__((ext_vector_type(8)));
typedef float   f32x4  __attribute__((ext_vector_type(4)));

#define BB 2
#define NN 2048
#define DD 1024
#define HH 16
#define HD 64
#define LOG2E   1.44269504f
#define SCALE_Q 0.18033688f   /* 0.125 * log2(e), folded into q */

// async global->LDS, 16B/lane; LDS dest = wave-uniform base + lane*16
__device__ __forceinline__ void glds16(const bf16* g, bf16* l) {
    __builtin_amdgcn_global_load_lds((const __attribute__((address_space(1))) void*)g,
                                     (__attribute__((address_space(3))) void*)l, 16, 0, 0);
}
__device__ __forceinline__ unsigned short bfu(float x) {
    bf16 b = __float2bfloat16(x);
    return __builtin_bit_cast(unsigned short, b);
}

// ---------------------------------------------------------------------------
// prep (single launch): [0,2048) cast x ; [2048,3072) bias_perm PACKED BF16
// pairs (8-wave consumption order; halves the dominant attn traffic stream) ;
// [3072,3840) transpose Wqkv ; [3840,4096) coordproj.
// ---------------------------------------------------------------------------
__global__ __launch_bounds__(256) void prep(const float* __restrict__ x,
                                            const float* __restrict__ bias,
                                            const float* __restrict__ W,
                                            const float* __restrict__ coords,
                                            const float* __restrict__ relw,
                                            bf16* __restrict__ xb,
                                            unsigned* __restrict__ pbh,
                                            bf16* __restrict__ Wt,
                                            bf16* __restrict__ cpn) {
    __shared__ bf16 tsm[64][65];
    const int bid = blockIdx.x, tid = threadIdx.x;
    if (bid < 2048) {
        size_t i = ((size_t)bid * 256 + tid) * 8;
        float4 a = *(const float4*)(x + i);
        float4 b = *(const float4*)(x + i + 4);
        bf16 t[8];
        t[0] = __float2bfloat16(a.x); t[1] = __float2bfloat16(a.y);
        t[2] = __float2bfloat16(a.z); t[3] = __float2bfloat16(a.w);
        t[4] = __float2bfloat16(b.x); t[5] = __float2bfloat16(b.y);
        t[6] = __float2bfloat16(b.z); t[7] = __float2bfloat16(b.w);
        *(int4*)(xb + i) = *(int4*)t;
    } else if (bid < 3072) {
        // pbh[tt*8 + m] packs bf16(log2e*bias) rows (quad*4+(m&1)*2, +1) at
        // col kt*64+(m>>1)*16+l15 ; tt = ((Qb*32+kt)*8+wave)*64+lane
        int tt   = (bid - 2048) * 256 + tid;     // 0..262143
        int lane = tt & 63;
        int wave = (tt >> 6) & 7;
        int kt   = (tt >> 9) & 31;
        int Qb   = tt >> 14;
        int quad = lane >> 4, l15 = lane & 15;
        unsigned pk[8];
#pragma unroll
        for (int m = 0; m < 8; ++m) {
            int g = m >> 1, rp = m & 1;
            int q = Qb * 128 + wave * 16 + quad * 4 + rp * 2;
            int k = kt * 64 + g * 16 + l15;
            float v0 = LOG2E * bias[(size_t)q * NN + k];
            float v1 = LOG2E * bias[(size_t)(q + 1) * NN + k];
            pk[m] = (unsigned)bfu(v0) | ((unsigned)bfu(v1) << 16);
        }
        int4* dst = (int4*)(pbh + (size_t)tt * 8);
        dst[0] = ((int4*)pk)[0];
        dst[1] = ((int4*)pk)[1];
    } else if (bid < 3840) {
        int idx = bid - 3072;                    // 0..767
        int n0 = (idx % 48) * 64;
        int k0 = (idx / 48) * 64;
        int tx = tid & 63, tg = tid >> 6;
#pragma unroll
        for (int i = 0; i < 16; ++i) {
            int r = tg + i * 4;
            tsm[r][tx] = __float2bfloat16(W[(size_t)(k0 + r) * 3072 + n0 + tx]);
        }
        __syncthreads();
#pragma unroll
        for (int i = 0; i < 16; ++i) {
            int r = tg + i * 4;
            Wt[(size_t)(n0 + r) * 1024 + k0 + tx] = tsm[tx][r];
        }
    } else {
        int idx = (bid - 3840) * 256 + tid;      // 0..65535
        int n  = idx & (NN - 1);
        int bh = idx >> 11;
        int h  = bh & (HH - 1);
        int b  = bh >> 4;
        float acc = 0.f;
#pragma unroll
        for (int c = 0; c < 3; ++c)
            acc += coords[(size_t)(b * NN + n) * 3 + c] * relw[h * 3 + c];
        cpn[idx] = __float2bfloat16(-LOG2E * acc);
    }
}

// ---------------------------------------------------------------------------
// qkv GEMM: 128x128 tile, BK=32 (R1 loop) + XCD-aware m-grouped block
// swizzle: xcd = gid&7 pins 4 contiguous m-panels per XCD (X stays L2-
// resident, ~1MB); within an XCD blocks run m-fastest so Wt streams once.
// Bijective: 768 = 8 xcd * 4 m * 24 n. V written DIRECTLY TRANSPOSED
// (bh,d,n); q pre-scaled by SCALE_Q.
// ---------------------------------------------------------------------------
__global__ __launch_bounds__(256) void qkv_gemm(const bf16* __restrict__ X,
                                                const bf16* __restrict__ W,
                                                const float* __restrict__ bq,
                                                bf16* __restrict__ qo,
                                                bf16* __restrict__ ko,
                                                bf16* __restrict__ vt) {
    __shared__ __align__(16) bf16 As[128 * 32];
    __shared__ __align__(16) bf16 Bs[128 * 32];
    const int tid  = threadIdx.x;
    const int gid  = blockIdx.x + blockIdx.y * 24;   // 0..767
    const int xcd  = gid & 7;                        // HW round-robin XCD
    const int idx  = gid >> 3;                       // 0..95 within XCD
    const int n0   = (idx >> 2) * 128;               // n-block 0..23 (m-fastest order)
    const int m0   = (xcd * 4 + (idx & 3)) * 128;    // 4 contiguous m-panels per XCD
    const int wave = tid >> 6, lane = tid & 63, l15 = lane & 15, quad = lane >> 4;
    const int wm   = wave >> 1, wn = wave & 1;

    f32x4 acc[4][4];
    const f32x4 z4 = {0.f, 0.f, 0.f, 0.f};
#pragma unroll
    for (int i = 0; i < 4; ++i)
#pragma unroll
        for (int j = 0; j < 4; ++j) acc[i][j] = z4;

    for (int kt = 0; kt < 1024; kt += 32) {
        __syncthreads();
#pragma unroll
        for (int j = 0; j < 2; ++j) {
            int s   = (wave * 2 + j) * 64 + lane;       // 0..511
            int row = s >> 2;                           // 0..127
            int c   = (s & 3) ^ ((row >> 1) & 3);       // swizzled col-block
            glds16(X + (size_t)(m0 + row) * 1024 + kt + c * 8, As + (wave * 2 + j) * 512);
            glds16(W + (size_t)(n0 + row) * 1024 + kt + c * 8, Bs + (wave * 2 + j) * 512);
        }
        __syncthreads();

        bf16x8 a[4], b[4];
#pragma unroll
        for (int mt = 0; mt < 4; ++mt) {
            int ra = wm * 64 + mt * 16 + l15;
            a[mt] = *(const bf16x8*)&As[ra * 32 + ((quad ^ ((ra >> 1) & 3)) * 8)];
        }
#pragma unroll
        for (int nt = 0; nt < 4; ++nt) {
            int rb = wn * 64 + nt * 16 + l15;
            b[nt] = *(const bf16x8*)&Bs[rb * 32 + ((quad ^ ((rb >> 1) & 3)) * 8)];
        }
#pragma unroll
        for (int mt = 0; mt < 4; ++mt)
#pragma unroll
            for (int nt = 0; nt < 4; ++nt)
                acc[mt][nt] = __builtin_amdgcn_mfma_f32_16x16x32_bf16(a[mt], b[nt], acc[mt][nt], 0, 0, 0);
    }

#pragma unroll
    for (int nt = 0; nt < 4; ++nt) {
        int c    = n0 + wn * 64 + nt * 16 + l15;   // 0..3071, tsel uniform per nt
        int tsel = c >> 10;
        int rem  = c & 1023;
        int h    = rem >> 6, d = rem & 63;
        float bias = bq[c];
        float qs   = (tsel == 0) ? SCALE_Q : 1.0f;
#pragma unroll
        for (int mt = 0; mt < 4; ++mt)
#pragma unroll
            for (int r = 0; r < 4; ++r) {
                int m = m0 + wm * 64 + mt * 16 + quad * 4 + r;   // 0..4095
                int b = m >> 11, n = m & (NN - 1);
                bf16 val = __float2bfloat16((acc[mt][nt][r] + bias) * qs);
                if (tsel == 2)
                    vt[((size_t)(b * HH + h) * HD + d) * NN + n] = val;
                else
                    ((tsel == 1) ? ko : qo)[((size_t)(b * HH + h) * NN + n) * HD + d] = val;
            }
    }
}

// ---------------------------------------------------------------------------
// flash attention v5: R1 structure (512 thr = 8 waves x 16 q, 128 q/block,
// grid 512) + PACKED BF16 bias (2 int4 loads/tile instead of 4; unpack via
// shift/mask into the MFMA C-operand). Bias stream 536->268 MB logical.
// LDS 55296 B.
// ---------------------------------------------------------------------------
__global__ __launch_bounds__(512, 4) void attn(const bf16* __restrict__ Q,
                                               const bf16* __restrict__ K,
                                               const bf16* __restrict__ Vt_g,
                                               const bf16* __restrict__ cpn_g,
                                               const unsigned* __restrict__ pbh,
                                               float* __restrict__ out) {
    __shared__ __align__(16) bf16 Ks[2][64 * 64];
    __shared__ __align__(16) bf16 Vs[2][64 * 64];      // [d][key]
    __shared__ __align__(16) unsigned PsW[8][16 * 36]; // packed P, per-wave
    __shared__ __align__(16) bf16 cpl[NN];             // -log2e * cp[bh][*]
    const int tid  = threadIdx.x;
    const int Qb   = blockIdx.x;           // 0..15
    const int bh   = blockIdx.y;           // 0..31
    const int b    = bh >> 4, h = bh & 15;
    const int q0   = Qb * 128;
    const int wave = tid >> 6, lane = tid & 63, l15 = lane & 15, quad = lane >> 4;
    const size_t base = (size_t)bh * NN * HD;

    // stage cp row (4 KB) with waves 0..3 (wave-uniform branch)
    if (wave < 4)
        glds16(cpn_g + bh * NN + (wave * 64 + lane) * 8, cpl + wave * 512);

    // Q fragments: 16 q-rows per wave, in registers for the whole kernel
    const int qrow = q0 + wave * 16 + l15;
    bf16x8 qf0 = *(const bf16x8*)&Q[base + (size_t)qrow * HD + quad * 8];
    bf16x8 qf1 = *(const bf16x8*)&Q[base + (size_t)qrow * HD + 32 + quad * 8];

    // hoisted staging geometry (one glds per buffer per wave)
    const int ps   = wave * 64 + lane;     // 0..511
    const int prow = ps >> 3;              // 0..63
    const int pcol = (ps & 7) ^ (prow & 7);

    // prologue: stage tile 0 into buffer 0
    glds16(K    + base + (size_t)prow * HD + pcol * 8, Ks[0] + wave * 512);
    glds16(Vt_g + base + (size_t)prow * NN + pcol * 8, Vs[0] + wave * 512);

    // bias: permuted packed bf16, register double-buffer. tile stride 4096 u32.
    const unsigned* bptr = pbh + ((((size_t)Qb * 32) * 8 + wave) * 64 + lane) * 8;
    unsigned bvA[8], bvB[8];
    *(int4*)&bvA[0] = ((const int4*)bptr)[0];
    *(int4*)&bvA[4] = ((const int4*)bptr)[1];

    const f32x4 z4 = {0.f, 0.f, 0.f, 0.f};
    f32x4 l4 = z4;
    f32x4 o[4];
#pragma unroll
    for (int t = 0; t < 4; ++t) o[t] = z4;

#define ATTN_TILE(T, CUR, BVC, BVN)                                               \
    {                                                                             \
        __syncthreads();   /* buf[CUR] ready (vmcnt drained); buf[CUR^1] free */  \
        if ((T) < 31) {    /* prefetch K/V tile T+1 and bias T+1 */               \
            int kk1 = ((T) + 1) * 64;                                             \
            glds16(K    + base + (size_t)(kk1 + prow) * HD + pcol * 8,            \
                   Ks[(CUR) ^ 1] + wave * 512);                                   \
            glds16(Vt_g + base + (size_t)prow * NN + kk1 + pcol * 8,              \
                   Vs[(CUR) ^ 1] + wave * 512);                                   \
            const unsigned* bp = bptr + (size_t)((T) + 1) * 4096;                 \
            *(int4*)&BVN[0] = ((const int4*)bp)[0];                               \
            *(int4*)&BVN[4] = ((const int4*)bp)[1];                               \
        }                                                                         \
        /* --- QK^T with C = bias' + mg (bias unpacked bf16->f32 into C) */       \
        f32x4 p4[4];                                                              \
        _Pragma("unroll")                                                         \
        for (int g = 0; g < 4; ++g) {                                             \
            float mgv = __bfloat162float(cpl[(T) * 64 + g * 16 + l15]);           \
            unsigned ba = BVC[g * 2], bb2 = BVC[g * 2 + 1];                       \
            f32x4 c0;                                                             \
            c0[0] = __builtin_bit_cast(float, ba << 16) + mgv;                    \
            c0[1] = __builtin_bit_cast(float, ba & 0xffff0000u) + mgv;            \
            c0[2] = __builtin_bit_cast(float, bb2 << 16) + mgv;                   \
            c0[3] = __builtin_bit_cast(float, bb2 & 0xffff0000u) + mgv;           \
            int krow = g * 16 + l15, sw = krow & 7;                               \
            bf16x8 k0 = *(const bf16x8*)&Ks[(CUR)][krow * 64 + ((quad ^ sw) * 8)];         \
            bf16x8 k1 = *(const bf16x8*)&Ks[(CUR)][krow * 64 + (((4 + quad) ^ sw) * 8)];   \
            f32x4 s4 = __builtin_amdgcn_mfma_f32_16x16x32_bf16(qf0, k0, c0, 0, 0, 0);      \
            s4 = __builtin_amdgcn_mfma_f32_16x16x32_bf16(qf1, k1, s4, 0, 0, 0);   \
            f32x4 e;                                                              \
            e[0] = __builtin_amdgcn_exp2f(s4[0]);                                 \
            e[1] = __builtin_amdgcn_exp2f(s4[1]);                                 \
            e[2] = __builtin_amdgcn_exp2f(s4[2]);                                 \
            e[3] = __builtin_amdgcn_exp2f(s4[3]);                                 \
            p4[g] = e;                                                            \
            l4 = l4 + e;                                                          \
        }                                                                         \
        /* --- packed P write (8 b32), one wait, read back as A-frags */          \
        _Pragma("unroll")                                                         \
        for (int g2 = 0; g2 < 2; ++g2)                                            \
            _Pragma("unroll")                                                     \
            for (int r = 0; r < 4; ++r) {                                         \
                unsigned pk = (unsigned)bfu(p4[g2][r]) |                          \
                              ((unsigned)bfu(p4[g2 + 2][r]) << 16);               \
                PsW[wave][(quad * 4 + r) * 36 + g2 * 16 + l15] = pk;              \
            }                                                                     \
        asm volatile("s_waitcnt lgkmcnt(0)" ::: "memory");                        \
        const int4* pr = (const int4*)&PsW[wave][l15 * 36 + quad * 8];            \
        int4 da = pr[0], db = pr[1];                                              \
        union { unsigned u[4]; bf16x8 v; } u0, u1;                                \
        u0.u[0] = __builtin_amdgcn_perm(da.y, da.x, 0x05040100u);                 \
        u0.u[1] = __builtin_amdgcn_perm(da.w, da.z, 0x05040100u);                 \
        u0.u[2] = __builtin_amdgcn_perm(db.y, db.x, 0x05040100u);                 \
        u0.u[3] = __builtin_amdgcn_perm(db.w, db.z, 0x05040100u);                 \
        u1.u[0] = __builtin_amdgcn_perm(da.y, da.x, 0x07060302u);                 \
        u1.u[1] = __builtin_amdgcn_perm(da.w, da.z, 0x07060302u);                 \
        u1.u[2] = __builtin_amdgcn_perm(db.y, db.x, 0x07060302u);                 \
        u1.u[3] = __builtin_amdgcn_perm(db.w, db.z, 0x07060302u);                 \
        /* --- PV (V frags loaded at use) */                                      \
        __builtin_amdgcn_s_setprio(1);                                            \
        _Pragma("unroll")                                                         \
        for (int tt = 0; tt < 4; ++tt) {                                          \
            int drow = tt * 16 + l15, sw2 = drow & 7;                             \
            bf16x8 v0 = *(const bf16x8*)&Vs[(CUR)][drow * 64 + ((quad ^ sw2) * 8)];        \
            bf16x8 v1 = *(const bf16x8*)&Vs[(CUR)][drow * 64 + (((4 + quad) ^ sw2) * 8)];  \
            o[tt] = __builtin_amdgcn_mfma_f32_16x16x32_bf16(u0.v, v0, o[tt], 0, 0, 0);     \
            o[tt] = __builtin_amdgcn_mfma_f32_16x16x32_bf16(u1.v, v1, o[tt], 0, 0, 0);     \
        }                                                                         \
        __builtin_amdgcn_s_setprio(0);                                            \
    }

    for (int t = 0; t < 32; t += 2) {
        ATTN_TILE(t,     0, bvA, bvB)
        ATTN_TILE(t + 1, 1, bvB, bvA)
    }
#undef ATTN_TILE

    // final l reduction (16 lanes per quad-row) + fp32 stores
    float l_loc[4] = {l4[0], l4[1], l4[2], l4[3]};
#pragma unroll
    for (int r = 0; r < 4; ++r) {
#pragma unroll
        for (int d = 1; d < 16; d <<= 1)
            l_loc[r] += __shfl_xor(l_loc[r], d, 64);
        float inv = 1.0f / l_loc[r];
        int qq = q0 + wave * 16 + quad * 4 + r;
#pragma unroll
        for (int tt = 0; tt < 4; ++tt)
            out[((size_t)(b * NN + qq)) * DD + h * HD + tt * 16 + l15] =
                o[tt][r] * inv;
    }
}

// ---------------------------------------------------------------------------
extern "C" void kernel_launch(void* const* d_in, const int* in_sizes, int n_in,
                              void* d_out, int out_size, void* d_ws, size_t ws_size,
                              hipStream_t stream) {
    const float* x      = (const float*)d_in[0];
    const float* coords = (const float*)d_in[1];
    const float* abias  = (const float*)d_in[2];
    const float* Wqkv   = (const float*)d_in[3];
    const float* bqkv   = (const float*)d_in[4];
    const float* relw   = (const float*)d_in[5];
    float* out = (float*)d_out;

    char* ws = (char*)d_ws;
    bf16*     xb  = (bf16*)(ws);                      // 8 MB
    bf16*     qw  = (bf16*)(ws + 8388608);            // 8 MB
    bf16*     kw  = (bf16*)(ws + 16777216);           // 8 MB
    bf16*     vt  = (bf16*)(ws + 25165824);           // 8 MB (bh,d,n) via gemm epilogue
    bf16*     Wt  = (bf16*)(ws + 33554432);           // 6 MB
    unsigned* pbh = (unsigned*)(ws + 39845888);       // 8.4 MB permuted bias packed bf16
    bf16*     cpb = (bf16*)(ws + 56623104);           // 128 KB

    prep    <<<dim3(4096),   256, 0, stream>>>(x, abias, Wqkv, coords, relw,
                                               xb, pbh, Wt, cpb);
    qkv_gemm<<<dim3(24, 32), 256, 0, stream>>>(xb, Wt, bqkv, qw, kw, vt);
    attn    <<<dim3(16, 32), 512, 0, stream>>>(qw, kw, vt, cpb, pbh, out);
}